// Round 6
// baseline (348.879 us; speedup 1.0000x reference)
//
#include <hip/hip_runtime.h>

#define CCH   640
#define RDIM  128
#define HWPIX 100
#define NBS   25
#define NBQ   75
#define CKK   5760
#define SF_B  64000

// ---------------- Workspace layout (float offsets) ----------------
#define OFF_A4T   0        // [640][9]
#define OFF_BETA  5760     // [16]
#define OFF_CKT   5776     // [25][5760]
#define OFF_CKS   149776   // [25][5760]
#define OFF_SKT   293776   // [25][900]  layout [b][uv*100+p]
#define OFF_SKS   316276   // [9][25][100] layout [uv][b][p]
#define OFF_TASKT 338776   // [9][640][100]

// K1: blocks 0..24: full pooled path for support image b (pool -> 4 GEMV chain
// -> mlp1 -> mlp2 -> CKT/CKS). Blocks 25..33: full A-chain for row k -> A4T, beta.
__global__ __launch_bounds__(1024) void prelude(
        const float* __restrict__ sf,
        const float* __restrict__ Wc0, const float* __restrict__ bc0,
        const float* __restrict__ Wc1, const float* __restrict__ bc1,
        const float* __restrict__ Wc2, const float* __restrict__ bc2,
        const float* __restrict__ Wc3, const float* __restrict__ bc3,
        const float* __restrict__ W1,  const float* __restrict__ b1,
        const float* __restrict__ W2,  const float* __restrict__ b2,
        const float* __restrict__ Ws,  const float* __restrict__ bs,
        float* __restrict__ CKT, float* __restrict__ CKS,
        float* __restrict__ A4T, float* __restrict__ Beta) {
    __shared__ float p0[CCH], pa[CCH], pb[CCH];
    __shared__ float hpart[8][RDIM];
    __shared__ float hs[2][RDIM];
    __shared__ float red[1024];
    __shared__ float betaS;

    const float* Wcf[4] = {Wc0, Wc1, Wc2, Wc3};
    const float* bcf[4] = {bc0, bc1, bc2, bc3};

    int blk = blockIdx.x, t = threadIdx.x;
    int wv = t >> 6, lane = t & 63;

    if (blk < NBS) {
        int b = blk;
        // ---- pool ----
        if (t < CCH) {
            const float4* s4 = (const float4*)(sf + b * SF_B + t * HWPIX);
            float acc = 0.f;
#pragma unroll
            for (int q = 0; q < 25; ++q) {
                float4 v = s4[q];
                acc += (v.x + v.y) + (v.z + v.w);
            }
            float pv = acc * 0.01f;
            p0[t] = pv;
            pa[t] = pv;
        }
        __syncthreads();
        // ---- 4 chained GEMVs: wave per output ----
        for (int s = 0; s < 4; ++s) {
            const float* W = Wcf[s];
            const float* bias = bcf[s];
            float* pin  = (s & 1) ? pb : pa;
            float* pout = (s & 1) ? pa : pb;
#pragma unroll 2
            for (int g = 0; g < 40; ++g) {
                int o = g * 16 + wv;
                const float* wrow = W + o * CCH;
                float acc = 0.f;
#pragma unroll
                for (int s5 = 0; s5 < 10; ++s5)
                    acc += wrow[s5 * 64 + lane] * pin[s5 * 64 + lane];
#pragma unroll
                for (int m = 32; m >= 1; m >>= 1) acc += __shfl_xor(acc, m);
                if (lane == 0) pout[o] = acc + bias[o];
            }
            __syncthreads();
        }
        // final pooled (task branch) in pa; instance pooled in p0
        // ---- mlp1: 2 branches x 4 K-slices x 128 r = 1024 threads ----
        {
            int r = t & 127, sl = (t >> 7) & 3, br = t >> 9;
            const float* pv = br ? p0 : pa;
            int c0 = sl * 160;
            float acc = 0.f;
#pragma unroll 8
            for (int c = 0; c < 160; ++c)
                acc += pv[c0 + c] * W1[(c0 + c) * RDIM + r];
            hpart[br * 4 + sl][r] = acc;
        }
        __syncthreads();
        if (t < 256) {
            int br = t >> 7, r = t & 127;
            hs[br][r] = fmaxf(b1[r] + hpart[br * 4][r] + hpart[br * 4 + 1][r]
                              + hpart[br * 4 + 2][r] + hpart[br * 4 + 3][r], 0.f);
        }
        __syncthreads();
        // ---- mlp2: both branches ----
        for (int j = t; j < CKK; j += 1024) {
            float a0 = b2[j], a1 = a0;
#pragma unroll 8
            for (int r = 0; r < RDIM; ++r) {
                float wvv = W2[r * CKK + j];
                a0 += hs[0][r] * wvv;
                a1 += hs[1][r] * wvv;
            }
            CKT[b * CKK + j] = a0;
            CKS[b * CKK + j] = a1;
        }
    } else {
        int k = blk - NBS;
        const float* WcR[4] = {Wc3, Wc2, Wc1, Wc0};
        const float* bcR[4] = {bc3, bc2, bc1, bc0};
        if (t < CCH) pa[t] = Ws[k * CCH + t];
        if (t == 0) betaS = bs[k];
        __syncthreads();
        for (int s = 0; s < 4; ++s) {
            const float* W = WcR[s];
            const float* bcv = bcR[s];
            float* pin  = (s & 1) ? pb : pa;
            float* pout = (s & 1) ? pa : pb;
            red[t] = (t < CCH) ? pin[t] * bcv[t] : 0.f;
            float acc = 0.f;
            if (t < CCH) {
#pragma unroll 8
                for (int o = 0; o < CCH; ++o)
                    acc += pin[o] * W[o * CCH + t];
            }
            __syncthreads();
            if (t < 64) {
                float ssum = 0.f;
#pragma unroll
                for (int m = 0; m < 16; ++m) ssum += red[m * 64 + t];
#pragma unroll
                for (int mm = 32; mm >= 1; mm >>= 1) ssum += __shfl_xor(ssum, mm);
                if (t == 0) betaS += ssum;
            }
            if (t < CCH) pout[t] = acc;
            __syncthreads();
        }
        if (t < CCH) A4T[t * 9 + k] = pa[t];   // after 4 steps result is in pa
        if (t == 0) Beta[k] = betaS;
    }
}

// K2: sk for both branches, shared x loads, full 640 dot.
// skT stored [b][uv*100+p]; skS stored [uv][b][p] (involution layout).
__global__ void sk_both(const float* __restrict__ sf, const float* __restrict__ A4T,
                        const float* __restrict__ Beta, const float* __restrict__ Ws,
                        const float* __restrict__ bs, float* __restrict__ SKT,
                        float* __restrict__ SKS) {
    int idx = blockIdx.x * 256 + threadIdx.x;
    if (idx >= NBS * 900) return;
    int b = idx / 900, r2 = idx % 900;       // flat f = k*100 + q
    int k = r2 / HWPIX, q = r2 % HWPIX;
    const float* x = sf + b * SF_B + q;
    const float* wsr = Ws + k * CCH;
    float a0 = Beta[k], a1 = bs[k];
#pragma unroll 8
    for (int c = 0; c < CCH; ++c) {
        float xc = x[c * HWPIX];
        a0 += A4T[c * 9 + k] * xc;
        a1 += wsr[c] * xc;
    }
    int p = r2 / 9, uv = r2 % 9;             // view coords
    SKT[b * 900 + uv * 100 + p] = a0;
    SKS[uv * 2500 + b * 100 + p] = a1;
}

// K3: taskT[uv*64000 + c*100 + p] = (1/25) sum_b CKT[b][c*9+uv] * SKT[b][uv*100+p]
__global__ void task_assemble(const float* __restrict__ CKT, const float* __restrict__ SKT,
                              float* __restrict__ taskT) {
    int idx = blockIdx.x * 256 + threadIdx.x;   // 576000
    int uv = idx / 64000;
    int rem = idx % 64000;
    int c = rem / 100, p = rem % 100;
    float acc = 0.f;
#pragma unroll
    for (int b = 0; b < NBS; ++b)
        acc += CKT[b * CKK + c * 9 + uv] * SKT[b * 900 + uv * 100 + p];
    taskT[idx] = acc * 0.04f;
}

// K4: merged involutions, thread per output element, transposed layouts (R5 design).
__global__ __launch_bounds__(256) void involutions(
        const float* __restrict__ sf, const float* __restrict__ qf,
        const float* __restrict__ taskT, const float* __restrict__ cks,
        const float* __restrict__ sksT, float* __restrict__ out) {
    int idx = blockIdx.x * 256 + threadIdx.x;     // 6.4M
    bool support = idx < NBS * SF_B;
    int b, c, p;
    const float* x;
    if (support) {
        b = idx / SF_B; int rem = idx % SF_B; c = rem / 100; p = rem % 100;
        x = sf + b * SF_B + c * 100;
    } else {
        int qidx = idx - NBS * SF_B;
        b = qidx / SF_B; int rem = qidx % SF_B; c = rem / 100; p = rem % 100;
        x = qf + b * SF_B + c * 100;
    }
    int i = p / 10, j = p % 10;
    float acc = 0.f;
#pragma unroll
    for (int u = 0; u < 3; ++u) {
        int ii = i + u - 1;
        float mrow = ((unsigned)ii < 10u) ? 1.f : 0.f;
        int ci = min(max(ii, 0), 9);
#pragma unroll
        for (int v = 0; v < 3; ++v) {
            int jj = j + v - 1;
            float m = ((unsigned)jj < 10u) ? mrow : 0.f;
            int cj = min(max(jj, 0), 9);
            float xv = x[ci * 10 + cj] * m;
            int uv = u * 3 + v;
            float w = taskT[uv * 64000 + c * 100 + p];
            if (support)
                w *= cks[b * CKK + c * 9 + uv] * sksT[uv * 2500 + b * 100 + p];
            acc += w * xv;
        }
    }
    out[idx] = acc;
}

extern "C" void kernel_launch(void* const* d_in, const int* in_sizes, int n_in,
                              void* d_out, int out_size, void* d_ws, size_t ws_size,
                              hipStream_t stream) {
    const float* sf  = (const float*)d_in[0];
    const float* qf  = (const float*)d_in[1];
    const float* Wc0 = (const float*)d_in[2];
    const float* bc0 = (const float*)d_in[3];
    const float* Wc1 = (const float*)d_in[4];
    const float* bc1 = (const float*)d_in[5];
    const float* Wc2 = (const float*)d_in[6];
    const float* bc2 = (const float*)d_in[7];
    const float* Wc3 = (const float*)d_in[8];
    const float* bc3 = (const float*)d_in[9];
    const float* W1 = (const float*)d_in[10];
    const float* b1 = (const float*)d_in[11];
    const float* W2 = (const float*)d_in[12];
    const float* b2 = (const float*)d_in[13];
    const float* Ws = (const float*)d_in[14];
    const float* bs = (const float*)d_in[15];
    float* out = (float*)d_out;
    float* ws = (float*)d_ws;

    float* A4T = ws + OFF_A4T;
    float* Bet = ws + OFF_BETA;
    float* CKT = ws + OFF_CKT;
    float* CKS = ws + OFF_CKS;
    float* SKT = ws + OFF_SKT;
    float* SKS = ws + OFF_SKS;
    float* TKT = ws + OFF_TASKT;

    prelude<<<34, 1024, 0, stream>>>(sf, Wc0, bc0, Wc1, bc1, Wc2, bc2, Wc3, bc3,
                                     W1, b1, W2, b2, Ws, bs, CKT, CKS, A4T, Bet);
    sk_both<<<88, 256, 0, stream>>>(sf, A4T, Bet, Ws, bs, SKT, SKS);
    task_assemble<<<2250, 256, 0, stream>>>(CKT, SKT, TKT);
    involutions<<<25000, 256, 0, stream>>>(sf, qf, TKT, CKS, SKS, out);
}